// Round 9
// baseline (646.407 us; speedup 1.0000x reference)
//
#include <hip/hip_runtime.h>
#include <math.h>

// ---------------------------------------------------------------------------
// GaussianQuant — MFMA-filtered argmax, R9.
// score[n,k] = sum_d p*c + q*c^2;  u=[p,q], v=[c,c^2], score = u.v  (K=64)
// fp16 hi/lo split (lo x2048):  v ~= uh.vh + (ul.vh + uh.vl)/2048
// Packed select: vq = (bits(v) & 0xFFFFFC00) | k_in_split  (10 bits).
// Sound bound (merge): Btot = (5e-6*S + 1e-4) + 2e-4*(|A*|+1);
// T = A* - 2*Btot; exact fp32 rescore of slice winners >= T + full rescan
// of slices with runner-up a2 >= T.
// R9: B staged via double-buffered LDS (shared by the block's 4 waves, 4x
// L2 traffic cut), XOR-swizzled slots (16-way -> 2-way bank conflict),
// chunk-ahead VGPR prefetch; cbpack+aprep fused; Bn computed in merge.
// ---------------------------------------------------------------------------

typedef _Float16 half8 __attribute__((ext_vector_type(8)));
typedef float f32x4 __attribute__((ext_vector_type(4)));

#define DIM 32
#define NTOK 2048
#define NROWS 16384
#define KSIZE 16384
#define NSPLIT 16
#define SPLITK 1024
#define NCHUNK 16                      // chunks of 4 tiles (64 k) per split
#define KMASK 0xFFFFFC00u              // clear low 10 bits (SPLITK=1024)

// ws layout (bytes); [0,4096) zeroed by memset each launch
#define WS_M1   0                       // 32 float (atomicMax targets)
#define WS_KL   256                     // 1 double (atomicAdd target)
#define WS_PQ   4096                    // 4 MB
#define WS_AH   (WS_PQ + 4194304)       // 2 MB fp16
#define WS_AL   (WS_AH + 2097152)       // 2 MB
#define WS_BH   (WS_AL + 2097152)       // 2 MB
#define WS_BL   (WS_BH + 2097152)       // 2 MB
#define WS_W1   (WS_BL + 2097152)       // 1 MB
#define WS_W2   (WS_W1 + 1048576)       // 1 MB

// Fused prep: blocks [0,256) pack codebook + per-dim |c| max;
// blocks [256,512) compute p,q + fp16 hi/lo pack + KL partial sum.
__global__ __launch_bounds__(256) void prep_kernel(const float* __restrict__ cb,
                                                   const float* __restrict__ z,
                                                   _Float16* __restrict__ Bh,
                                                   _Float16* __restrict__ Bl,
                                                   float* __restrict__ M1,
                                                   float* __restrict__ PQ,
                                                   _Float16* __restrict__ Ah,
                                                   _Float16* __restrict__ Al,
                                                   double* __restrict__ klsum) {
  const int w = threadIdx.x >> 6, l = threadIdx.x & 63;
  const int sub = l >> 5, d = l & 31;
  if (blockIdx.x < 256) {
    // ---- codebook pack + per-dim max ----
    __shared__ float lm[8][DIM];
    float m = 0.0f;
#pragma unroll
    for (int i = 0; i < 8; ++i) {
      const int k = blockIdx.x * 64 + i * 8 + w * 2 + sub;
      const float c = cb[k * DIM + d];
      const float c2 = c * c;
      const _Float16 ch = (_Float16)c;
      const _Float16 sh = (_Float16)c2;
      Bh[(size_t)k * 64 + d] = ch;
      Bh[(size_t)k * 64 + 32 + d] = sh;
      Bl[(size_t)k * 64 + d] = (_Float16)((c - (float)ch) * 2048.0f);
      Bl[(size_t)k * 64 + 32 + d] = (_Float16)((c2 - (float)sh) * 2048.0f);
      m = fmaxf(m, fabsf(c));
    }
    lm[threadIdx.x >> 5][d] = m;
    __syncthreads();
    if (threadIdx.x < DIM) {
      float x = lm[0][threadIdx.x];
#pragma unroll
      for (int i = 1; i < 8; ++i) x = fmaxf(x, lm[i][threadIdx.x]);
      atomicMax((unsigned*)&M1[threadIdx.x], __float_as_uint(x));
    }
  } else {
    // ---- A-side prep + KL ----
    const int blk = blockIdx.x - 256;
    double kacc = 0.0;
#pragma unroll 1
    for (int i = 0; i < 8; ++i) {
      const int row = blk * 64 + i * 8 + w * 2 + sub;
      const int t = row >> 3, c = row & 7;
      const float mu = z[t * 512 + d * 8 + c];
      float lv = z[t * 512 + 256 + d * 8 + c];
      lv = fminf(fmaxf(lv, -30.0f), 20.0f);
      const float stdv = expf(0.5f * lv);
      const float iv = 1.0f / (stdv * stdv);   // identical to R2 expression
      const float p = mu * iv;
      const float q = 0.5f * (1.0f - iv);
      PQ[(size_t)row * 64 + d] = p;
      PQ[(size_t)row * 64 + 32 + d] = q;
      const _Float16 ph = (_Float16)p;
      const _Float16 qh = (_Float16)q;
      Ah[(size_t)row * 64 + d] = ph;
      Ah[(size_t)row * 64 + 32 + d] = qh;
      Al[(size_t)row * 64 + d] = (_Float16)((p - (float)ph) * 2048.0f);
      Al[(size_t)row * 64 + 32 + d] = (_Float16)((q - (float)qh) * 2048.0f);
      kacc += (double)(mu * mu + stdv * stdv - 1.0f - lv);
    }
#pragma unroll
    for (int off = 32; off > 0; off >>= 1) kacc += __shfl_down(kacc, off);
    __shared__ double wsum[4];
    if (l == 0) wsum[w] = kacc;
    __syncthreads();
    if (threadIdx.x == 0)
      atomicAdd(klsum, (wsum[0] + wsum[1]) + (wsum[2] + wsum[3]));
  }
}

#define FTILE(VH0, VH1, VL0, VL1, KQ)                                         \
  {                                                                           \
    const unsigned kq_ = (KQ);                                                \
    _Pragma("unroll")                                                         \
    for (int rt = 0; rt < 4; ++rt) {                                          \
      f32x4 hh = {0.f, 0.f, 0.f, 0.f};                                        \
      hh = __builtin_amdgcn_mfma_f32_16x16x32_f16(uh0[rt], VH0, hh, 0, 0, 0); \
      hh = __builtin_amdgcn_mfma_f32_16x16x32_f16(uh1[rt], VH1, hh, 0, 0, 0); \
      f32x4 xc = {0.f, 0.f, 0.f, 0.f};                                        \
      xc = __builtin_amdgcn_mfma_f32_16x16x32_f16(ul0[rt], VH0, xc, 0, 0, 0); \
      xc = __builtin_amdgcn_mfma_f32_16x16x32_f16(ul1[rt], VH1, xc, 0, 0, 0); \
      xc = __builtin_amdgcn_mfma_f32_16x16x32_f16(uh0[rt], VL0, xc, 0, 0, 0); \
      xc = __builtin_amdgcn_mfma_f32_16x16x32_f16(uh1[rt], VL1, xc, 0, 0, 0); \
      _Pragma("unroll")                                                       \
      for (int r = 0; r < 4; ++r) {                                           \
        const float v = fmaf(xc[r], 1.0f / 2048.0f, hh[r]);                   \
        const float vq = __uint_as_float((__float_as_uint(v) & KMASK) | kq_); \
        a2[rt][r] = fmaxf(a2[rt][r], fminf(vq, a1[rt][r]));                   \
        a1[rt][r] = fmaxf(a1[rt][r], vq);                                     \
      }                                                                       \
    }                                                                         \
  }

// grid (64, 16): x = rowgroup (256 rows), y = split. 4 waves x 64 rows each.
// B staged through 32 KB double-buffered LDS (4 tiles = 64 k per chunk).
__global__ __launch_bounds__(256, 3) void filter_kernel(const _Float16* __restrict__ Ah,
                                                        const _Float16* __restrict__ Al,
                                                        const _Float16* __restrict__ Bh,
                                                        const _Float16* __restrict__ Bl,
                                                        float* __restrict__ W1,
                                                        float* __restrict__ W2) {
  __shared__ float4 smem[2048];   // [buf:2][arr:2][tile:4][slot:128] x 16B
  const int tid = threadIdx.x;
  const int lane = tid & 63;
  const int wave = tid >> 6;
  const int split = blockIdx.y;
  const int rowbase = blockIdx.x * 256 + wave * 64;   // 4 rowtiles of 16
  const int c16 = lane & 15, quad = lane >> 4;
  const unsigned c16u = (unsigned)c16;

  half8 uh0[4], uh1[4], ul0[4], ul1[4];
#pragma unroll
  for (int rt = 0; rt < 4; ++rt) {
    const size_t abase = (size_t)(rowbase + rt * 16 + c16) * 64 + quad * 8;
    uh0[rt] = *(const half8*)(Ah + abase);
    uh1[rt] = *(const half8*)(Ah + abase + 32);
    ul0[rt] = *(const half8*)(Al + abase);
    ul1[rt] = *(const half8*)(Al + abase + 32);
  }

  float a1[4][4], a2[4][4];
#pragma unroll
  for (int rt = 0; rt < 4; ++rt)
#pragma unroll
    for (int r = 0; r < 4; ++r) { a1[rt][r] = -INFINITY; a2[rt][r] = -INFINITY; }

  // staging indices: frag j = tid + i*256 (i<2) per array; kc = j>>3, f = j&7
  // swizzled slot (16B units): arr*512 + (kc>>4)*128 + (kc&15)*8 + ((f+(kc&15))&7)
  const size_t bbase = (size_t)split * SPLITK * 64;   // halfs
  int lidx[2][2];
  size_t goff[2][2];
#pragma unroll
  for (int arr = 0; arr < 2; ++arr)
#pragma unroll
    for (int i = 0; i < 2; ++i) {
      const int j = tid + i * 256;
      const int kc = j >> 3, f = j & 7;
      goff[arr][i] = (size_t)kc * 64 + f * 8;
      lidx[arr][i] = arr * 512 + (kc >> 4) * 128 + (kc & 15) * 8 + ((f + (kc & 15)) & 7);
    }

  // stage chunk 0 -> buf 0
#pragma unroll
  for (int arr = 0; arr < 2; ++arr)
#pragma unroll
    for (int i = 0; i < 2; ++i) {
      const _Float16* src = (arr ? Bl : Bh) + bbase + goff[arr][i];
      smem[lidx[arr][i]] = *(const float4*)src;
    }
  __syncthreads();

  // lane read slots (swizzled): vh0 f=quad, vh1 f=quad+4
  const int rs1 = c16 * 8 + ((quad + c16) & 7);
  const int rs2 = c16 * 8 + ((quad + 4 + c16) & 7);

#pragma unroll 1
  for (int ch = 0; ch < NCHUNK; ++ch) {
    const int b = ch & 1;
    float4 pre[2][2];
    if (ch + 1 < NCHUNK) {
#pragma unroll
      for (int arr = 0; arr < 2; ++arr)
#pragma unroll
        for (int i = 0; i < 2; ++i) {
          const _Float16* src = (arr ? Bl : Bh) + bbase +
                                (size_t)(ch + 1) * 4096 + goff[arr][i];
          pre[arr][i] = *(const float4*)src;
        }
    }
#pragma unroll
    for (int t = 0; t < 4; ++t) {
      const int base = b * 1024 + t * 128;
      const half8 vh0 = *(const half8*)&smem[base + rs1];
      const half8 vh1 = *(const half8*)&smem[base + rs2];
      const half8 vl0 = *(const half8*)&smem[base + 512 + rs1];
      const half8 vl1 = *(const half8*)&smem[base + 512 + rs2];
      FTILE(vh0, vh1, vl0, vl1, (unsigned)(ch * 64 + t * 16) + c16u);
    }
    __syncthreads();
    if (ch + 1 < NCHUNK) {
      const int ob = (ch + 1) & 1;
#pragma unroll
      for (int arr = 0; arr < 2; ++arr)
#pragma unroll
        for (int i = 0; i < 2; ++i)
          smem[ob * 1024 + lidx[arr][i]] = pre[arr][i];
    }
    __syncthreads();
  }

  // reduce packed top1+top2 across the 16 c16 lanes of each quad
#pragma unroll
  for (int rt = 0; rt < 4; ++rt)
#pragma unroll
    for (int r = 0; r < 4; ++r) {
      float x1 = a1[rt][r], x2 = a2[rt][r];
#pragma unroll
      for (int off = 1; off < 16; off <<= 1) {
        const float y1 = __shfl_xor(x1, off);
        const float y2 = __shfl_xor(x2, off);
        x2 = fmaxf(fmaxf(x2, y2), fminf(x1, y1));
        x1 = fmaxf(x1, y1);
      }
      if (c16 == 0) {
        const int row_r = rowbase + rt * 16 + quad * 4 + r;  // C: row=quad*4+reg
        W1[row_r * NSPLIT + split] = x1;
        W2[row_r * NSPLIT + split] = x2;
      }
    }
}

// exact fp32 score, p/q broadcast from LDS (identical formula to R2)
__device__ __forceinline__ float exact_score(const float4* __restrict__ cb4,
                                             const float4* __restrict__ spq,
                                             int k) {
  float s0 = 0.0f, s1 = 0.0f, s2 = 0.0f, s3 = 0.0f;
#pragma unroll
  for (int m = 0; m < 8; ++m) {
    const float4 cv = cb4[k * 8 + m];
    const float4 pv = spq[m];        // p[4m..4m+3]
    const float4 qv = spq[8 + m];    // q[4m..4m+3]
    s0 = fmaf(cv.x, fmaf(qv.x, cv.x, pv.x), s0);
    s1 = fmaf(cv.y, fmaf(qv.y, cv.y, pv.y), s1);
    s2 = fmaf(cv.z, fmaf(qv.z, cv.z, pv.z), s2);
    s3 = fmaf(cv.w, fmaf(qv.w, cv.w, pv.w), s3);
  }
  return (s0 + s1) + (s2 + s3);
}

// 1 wave per row; 4 rows per block. Fused: Bn calc + exact re-argmax +
// out2 + gather (out0) + out1 (kl scalar).
__global__ __launch_bounds__(256, 4) void merge_kernel(const float* __restrict__ PQ,
                                                       const float* __restrict__ cb,
                                                       const float* __restrict__ W1,
                                                       const float* __restrict__ W2,
                                                       const float* __restrict__ M1,
                                                       const double* __restrict__ klsum,
                                                       float* __restrict__ out0,
                                                       float* __restrict__ out1,
                                                       float* __restrict__ out2) {
  __shared__ float4 spq_s[4][16];
  const int lane = threadIdx.x & 63;
  const int wave = threadIdx.x >> 6;
  const int row = blockIdx.x * 4 + wave;

  if (lane < 16)
    spq_s[wave][lane] = ((const float4*)(PQ + (size_t)row * 64))[lane];
  __syncthreads();
  const float4* spq = spq_s[wave];
  const float4* __restrict__ cb4 = (const float4*)cb;

  // per-row rigorous bound S = sum |p|M1 + |q|M1^2
  float s = 0.0f;
  if (lane < DIM) {
    const float m1 = M1[lane];
    const float pd = ((const float*)spq)[lane];
    const float qd = ((const float*)spq)[32 + lane];
    s = fabsf(pd) * m1 + fabsf(qd) * m1 * m1;
  }
#pragma unroll
  for (int off = 1; off < 32; off <<= 1) s += __shfl_xor(s, off);
  const float Sn = __shfl(s, 0);

  float a1 = -INFINITY, a2 = -INFINITY;
  if (lane < NSPLIT) {
    a1 = W1[row * NSPLIT + lane];
    a2 = W2[row * NSPLIT + lane];
  }
  float As = a1;
#pragma unroll
  for (int off = 1; off < 64; off <<= 1) As = fmaxf(As, __shfl_xor(As, off));
  const float Btot = (5e-6f * Sn + 1e-4f) + 2e-4f * (fabsf(As) + 1.0f);
  const float T = As - 2.0f * Btot;

  float best = -INFINITY;
  int bk = 0x7FFFFFFF;
  if (lane < NSPLIT && a1 >= T) {              // candidate slice winners (~1)
    bk = lane * SPLITK + (int)(__float_as_uint(a1) & 1023u);
    best = exact_score(cb4, spq, bk);
  }
  unsigned long long mflag = __ballot(lane < NSPLIT && a2 >= T);
#pragma unroll 1
  while (mflag) {
    const int sl = __builtin_ctzll(mflag);
    mflag &= mflag - 1;
#pragma unroll 1
    for (int j = 0; j < SPLITK / 64; ++j) {
      const int k = sl * SPLITK + lane * (SPLITK / 64) + j;
      const float sc = exact_score(cb4, spq, k);
      if (sc > best || (sc == best && k < bk)) { best = sc; bk = k; }
    }
  }
  // cross-lane argmax, min-k on ties (numpy first-max)
#pragma unroll
  for (int off = 1; off < 64; off <<= 1) {
    const float ov = __shfl_xor(best, off);
    const int ok = __shfl_xor(bk, off);
    if (ov > best || (ov == best && ok < bk)) { best = ov; bk = ok; }
  }
  if (lane == 0) out2[row] = (float)bk;
  const int tt = row >> 3, cc = row & 7;
  if (lane < DIM) out0[tt * 256 + lane * 8 + cc] = cb[bk * DIM + lane];
  if (blockIdx.x == 0 && threadIdx.x == 0)
    out1[0] = (float)(klsum[0] * (1.4426 * 0.5) / (double)NROWS);
}

extern "C" void kernel_launch(void* const* d_in, const int* in_sizes, int n_in,
                              void* d_out, int out_size, void* d_ws, size_t ws_size,
                              hipStream_t stream) {
  const float* z  = (const float*)d_in[0];
  const float* cb = (const float*)d_in[2];   // d_in[1]=noise unused (STE cancels)

  char* ws = (char*)d_ws;
  float*      M1 = (float*)(ws + WS_M1);
  double* klsum  = (double*)(ws + WS_KL);
  float*      PQ = (float*)(ws + WS_PQ);
  _Float16*   Ah = (_Float16*)(ws + WS_AH);
  _Float16*   Al = (_Float16*)(ws + WS_AL);
  _Float16*   Bh = (_Float16*)(ws + WS_BH);
  _Float16*   Bl = (_Float16*)(ws + WS_BL);
  float*      W1 = (float*)(ws + WS_W1);
  float*      W2 = (float*)(ws + WS_W2);

  float* out0 = (float*)d_out;            // 524288
  float* out1 = out0 + 524288;            // 1
  float* out2 = out1 + 1;                 // 16384

  (void)hipMemsetAsync(ws, 0, 4096, stream);       // M1, klsum = 0
  prep_kernel<<<512, 256, 0, stream>>>(cb, z, Bh, Bl, M1, PQ, Ah, Al, klsum);
  dim3 fgrid(64, NSPLIT);
  filter_kernel<<<fgrid, 256, 0, stream>>>(Ah, Al, Bh, Bl, W1, W2);
  merge_kernel<<<NROWS / 4, 256, 0, stream>>>(PQ, cb, W1, W2, M1, klsum,
                                              out0, out1, out2);
}

// Round 10
// 238.550 us; speedup vs baseline: 2.7097x; 2.7097x over previous
//
#include <hip/hip_runtime.h>
#include <math.h>

// ---------------------------------------------------------------------------
// GaussianQuant — MFMA-filtered argmax, R10.
// score[n,k] = sum_d p*c + q*c^2;  u=[p,q], v=[c,c^2], score = u.v  (K=64)
// fp16 hi/lo split (lo x2048):  v ~= uh.vh + (ul.vh + uh.vl)/2048
// Packed select: vq = (bits(v) & 0xFFFFFC00) | k_in_split  (10 bits).
// Sound bound (merge): Btot = (5e-6*S + 1e-4) + 2e-4*(|A*|+1);
// T = A* - 2*Btot; exact fp32 rescore of slice winners >= T + full rescan
// of slices with runner-up a2 >= T.
// R10: R8 direct-load ping-pong filter (R9's LDS staging spilled: 1.3 GB
// scratch writes) at 3 waves/EU (fits: ~144 < 170-reg cap), 128-thread
// blocks for dispatch balance, med3 top-2 select (5 -> 4 VALU/value).
// ---------------------------------------------------------------------------

typedef _Float16 half8 __attribute__((ext_vector_type(8)));
typedef float f32x4 __attribute__((ext_vector_type(4)));

#if defined(__has_builtin)
#if __has_builtin(__builtin_amdgcn_fmed3f)
#define MED3(a, b, c) __builtin_amdgcn_fmed3f((a), (b), (c))
#else
#define MED3(a, b, c) fmaxf((a), fminf((b), (c)))
#endif
#else
#define MED3(a, b, c) fmaxf((a), fminf((b), (c)))
#endif

#define DIM 32
#define NTOK 2048
#define NROWS 16384
#define KSIZE 16384
#define NSPLIT 16
#define SPLITK 1024
#define NTILES 64                      // k-tiles of 16 per split
#define KMASK 0xFFFFFC00u              // clear low 10 bits (SPLITK=1024)

// ws layout (bytes); [0,4096) zeroed by memset each launch
#define WS_M1   0                       // 32 float (atomicMax targets)
#define WS_KL   256                     // 1 double (atomicAdd target)
#define WS_PQ   4096                    // 4 MB
#define WS_AH   (WS_PQ + 4194304)       // 2 MB fp16
#define WS_AL   (WS_AH + 2097152)       // 2 MB
#define WS_BH   (WS_AL + 2097152)       // 2 MB
#define WS_BL   (WS_BH + 2097152)       // 2 MB
#define WS_W1   (WS_BL + 2097152)       // 1 MB
#define WS_W2   (WS_W1 + 1048576)       // 1 MB

// Fused prep: blocks [0,256) pack codebook + per-dim |c| max;
// blocks [256,512) compute p,q + fp16 hi/lo pack + KL partial sum.
__global__ __launch_bounds__(256) void prep_kernel(const float* __restrict__ cb,
                                                   const float* __restrict__ z,
                                                   _Float16* __restrict__ Bh,
                                                   _Float16* __restrict__ Bl,
                                                   float* __restrict__ M1,
                                                   float* __restrict__ PQ,
                                                   _Float16* __restrict__ Ah,
                                                   _Float16* __restrict__ Al,
                                                   double* __restrict__ klsum) {
  const int w = threadIdx.x >> 6, l = threadIdx.x & 63;
  const int sub = l >> 5, d = l & 31;
  if (blockIdx.x < 256) {
    __shared__ float lm[8][DIM];
    float m = 0.0f;
#pragma unroll
    for (int i = 0; i < 8; ++i) {
      const int k = blockIdx.x * 64 + i * 8 + w * 2 + sub;
      const float c = cb[k * DIM + d];
      const float c2 = c * c;
      const _Float16 ch = (_Float16)c;
      const _Float16 sh = (_Float16)c2;
      Bh[(size_t)k * 64 + d] = ch;
      Bh[(size_t)k * 64 + 32 + d] = sh;
      Bl[(size_t)k * 64 + d] = (_Float16)((c - (float)ch) * 2048.0f);
      Bl[(size_t)k * 64 + 32 + d] = (_Float16)((c2 - (float)sh) * 2048.0f);
      m = fmaxf(m, fabsf(c));
    }
    lm[threadIdx.x >> 5][d] = m;
    __syncthreads();
    if (threadIdx.x < DIM) {
      float x = lm[0][threadIdx.x];
#pragma unroll
      for (int i = 1; i < 8; ++i) x = fmaxf(x, lm[i][threadIdx.x]);
      atomicMax((unsigned*)&M1[threadIdx.x], __float_as_uint(x));
    }
  } else {
    const int blk = blockIdx.x - 256;
    double kacc = 0.0;
#pragma unroll 1
    for (int i = 0; i < 8; ++i) {
      const int row = blk * 64 + i * 8 + w * 2 + sub;
      const int t = row >> 3, c = row & 7;
      const float mu = z[t * 512 + d * 8 + c];
      float lv = z[t * 512 + 256 + d * 8 + c];
      lv = fminf(fmaxf(lv, -30.0f), 20.0f);
      const float stdv = expf(0.5f * lv);
      const float iv = 1.0f / (stdv * stdv);   // identical to R2 expression
      const float p = mu * iv;
      const float q = 0.5f * (1.0f - iv);
      PQ[(size_t)row * 64 + d] = p;
      PQ[(size_t)row * 64 + 32 + d] = q;
      const _Float16 ph = (_Float16)p;
      const _Float16 qh = (_Float16)q;
      Ah[(size_t)row * 64 + d] = ph;
      Ah[(size_t)row * 64 + 32 + d] = qh;
      Al[(size_t)row * 64 + d] = (_Float16)((p - (float)ph) * 2048.0f);
      Al[(size_t)row * 64 + 32 + d] = (_Float16)((q - (float)qh) * 2048.0f);
      kacc += (double)(mu * mu + stdv * stdv - 1.0f - lv);
    }
#pragma unroll
    for (int off = 32; off > 0; off >>= 1) kacc += __shfl_down(kacc, off);
    __shared__ double wsum[4];
    if (l == 0) wsum[w] = kacc;
    __syncthreads();
    if (threadIdx.x == 0)
      atomicAdd(klsum, (wsum[0] + wsum[1]) + (wsum[2] + wsum[3]));
  }
}

#define FTILE(VH0, VH1, VL0, VL1, KQ)                                         \
  {                                                                           \
    const unsigned kq_ = (KQ);                                                \
    _Pragma("unroll")                                                         \
    for (int rt = 0; rt < 4; ++rt) {                                          \
      f32x4 hh = {0.f, 0.f, 0.f, 0.f};                                        \
      hh = __builtin_amdgcn_mfma_f32_16x16x32_f16(uh0[rt], VH0, hh, 0, 0, 0); \
      hh = __builtin_amdgcn_mfma_f32_16x16x32_f16(uh1[rt], VH1, hh, 0, 0, 0); \
      f32x4 xc = {0.f, 0.f, 0.f, 0.f};                                        \
      xc = __builtin_amdgcn_mfma_f32_16x16x32_f16(ul0[rt], VH0, xc, 0, 0, 0); \
      xc = __builtin_amdgcn_mfma_f32_16x16x32_f16(ul1[rt], VH1, xc, 0, 0, 0); \
      xc = __builtin_amdgcn_mfma_f32_16x16x32_f16(uh0[rt], VL0, xc, 0, 0, 0); \
      xc = __builtin_amdgcn_mfma_f32_16x16x32_f16(uh1[rt], VL1, xc, 0, 0, 0); \
      _Pragma("unroll")                                                       \
      for (int r = 0; r < 4; ++r) {                                           \
        const float v = fmaf(xc[r], 1.0f / 2048.0f, hh[r]);                   \
        const float vq = __uint_as_float((__float_as_uint(v) & KMASK) | kq_); \
        a2[rt][r] = MED3(a2[rt][r], vq, a1[rt][r]);  /* a2<=a1 invariant */   \
        a1[rt][r] = fmaxf(a1[rt][r], vq);                                     \
      }                                                                       \
    }                                                                         \
  }

// grid (128, 16): x = rowgroup (128 rows), y = split. 2 waves x 64 rows.
__global__ __launch_bounds__(128, 3) void filter_kernel(const _Float16* __restrict__ Ah,
                                                        const _Float16* __restrict__ Al,
                                                        const _Float16* __restrict__ Bh,
                                                        const _Float16* __restrict__ Bl,
                                                        float* __restrict__ W1,
                                                        float* __restrict__ W2) {
  const int lane = threadIdx.x & 63;
  const int wave = threadIdx.x >> 6;
  const int split = blockIdx.y;
  const int rowbase = blockIdx.x * 128 + wave * 64;   // 4 rowtiles of 16
  const int c16 = lane & 15, quad = lane >> 4;
  const unsigned c16u = (unsigned)c16;

  half8 uh0[4], uh1[4], ul0[4], ul1[4];
#pragma unroll
  for (int rt = 0; rt < 4; ++rt) {
    const size_t abase = (size_t)(rowbase + rt * 16 + c16) * 64 + quad * 8;
    uh0[rt] = *(const half8*)(Ah + abase);
    uh1[rt] = *(const half8*)(Ah + abase + 32);
    ul0[rt] = *(const half8*)(Al + abase);
    ul1[rt] = *(const half8*)(Al + abase + 32);
  }

  float a1[4][4], a2[4][4];
#pragma unroll
  for (int rt = 0; rt < 4; ++rt)
#pragma unroll
    for (int r = 0; r < 4; ++r) { a1[rt][r] = -INFINITY; a2[rt][r] = -INFINITY; }

  const int k0 = split * SPLITK;
  const _Float16* pbh = Bh + (size_t)(k0 + c16) * 64 + quad * 8;
  const _Float16* pbl = Bl + (size_t)(k0 + c16) * 64 + quad * 8;

  // ping-pong prefetch: tile stride = 16 k * 64 halfs = 1024
  half8 bxh0 = *(const half8*)(pbh);
  half8 bxh1 = *(const half8*)(pbh + 32);
  half8 bxl0 = *(const half8*)(pbl);
  half8 bxl1 = *(const half8*)(pbl + 32);
#pragma unroll 1
  for (int t = 0; t < NTILES; t += 2) {
    const _Float16* p1h = pbh + (size_t)(t + 1) * 1024;
    const _Float16* p1l = pbl + (size_t)(t + 1) * 1024;
    const half8 byh0 = *(const half8*)(p1h);
    const half8 byh1 = *(const half8*)(p1h + 32);
    const half8 byl0 = *(const half8*)(p1l);
    const half8 byl1 = *(const half8*)(p1l + 32);
    FTILE(bxh0, bxh1, bxl0, bxl1, (unsigned)(t * 16) + c16u);
    const _Float16* p2h = pbh + (size_t)(t + 2) * 1024;   // harmless 2KB
    const _Float16* p2l = pbl + (size_t)(t + 2) * 1024;   // over-read at end
    bxh0 = *(const half8*)(p2h);
    bxh1 = *(const half8*)(p2h + 32);
    bxl0 = *(const half8*)(p2l);
    bxl1 = *(const half8*)(p2l + 32);
    FTILE(byh0, byh1, byl0, byl1, (unsigned)((t + 1) * 16) + c16u);
  }

  // reduce packed top1+top2 across the 16 c16 lanes of each quad
#pragma unroll
  for (int rt = 0; rt < 4; ++rt)
#pragma unroll
    for (int r = 0; r < 4; ++r) {
      float x1 = a1[rt][r], x2 = a2[rt][r];
#pragma unroll
      for (int off = 1; off < 16; off <<= 1) {
        const float y1 = __shfl_xor(x1, off);
        const float y2 = __shfl_xor(x2, off);
        x2 = fmaxf(fmaxf(x2, y2), fminf(x1, y1));
        x1 = fmaxf(x1, y1);
      }
      if (c16 == 0) {
        const int row_r = rowbase + rt * 16 + quad * 4 + r;  // C: row=quad*4+reg
        W1[row_r * NSPLIT + split] = x1;
        W2[row_r * NSPLIT + split] = x2;
      }
    }
}

// exact fp32 score, p/q broadcast from LDS (identical formula to R2)
__device__ __forceinline__ float exact_score(const float4* __restrict__ cb4,
                                             const float4* __restrict__ spq,
                                             int k) {
  float s0 = 0.0f, s1 = 0.0f, s2 = 0.0f, s3 = 0.0f;
#pragma unroll
  for (int m = 0; m < 8; ++m) {
    const float4 cv = cb4[k * 8 + m];
    const float4 pv = spq[m];        // p[4m..4m+3]
    const float4 qv = spq[8 + m];    // q[4m..4m+3]
    s0 = fmaf(cv.x, fmaf(qv.x, cv.x, pv.x), s0);
    s1 = fmaf(cv.y, fmaf(qv.y, cv.y, pv.y), s1);
    s2 = fmaf(cv.z, fmaf(qv.z, cv.z, pv.z), s2);
    s3 = fmaf(cv.w, fmaf(qv.w, cv.w, pv.w), s3);
  }
  return (s0 + s1) + (s2 + s3);
}

// 1 wave per row; 4 rows per block. Fused: Bn calc + exact re-argmax +
// out2 + gather (out0) + out1 (kl scalar).
__global__ __launch_bounds__(256, 4) void merge_kernel(const float* __restrict__ PQ,
                                                       const float* __restrict__ cb,
                                                       const float* __restrict__ W1,
                                                       const float* __restrict__ W2,
                                                       const float* __restrict__ M1,
                                                       const double* __restrict__ klsum,
                                                       float* __restrict__ out0,
                                                       float* __restrict__ out1,
                                                       float* __restrict__ out2) {
  __shared__ float4 spq_s[4][16];
  const int lane = threadIdx.x & 63;
  const int wave = threadIdx.x >> 6;
  const int row = blockIdx.x * 4 + wave;

  if (lane < 16)
    spq_s[wave][lane] = ((const float4*)(PQ + (size_t)row * 64))[lane];
  __syncthreads();
  const float4* spq = spq_s[wave];
  const float4* __restrict__ cb4 = (const float4*)cb;

  // per-row rigorous bound S = sum |p|M1 + |q|M1^2
  float s = 0.0f;
  if (lane < DIM) {
    const float m1 = M1[lane];
    const float pd = ((const float*)spq)[lane];
    const float qd = ((const float*)spq)[32 + lane];
    s = fabsf(pd) * m1 + fabsf(qd) * m1 * m1;
  }
#pragma unroll
  for (int off = 1; off < 32; off <<= 1) s += __shfl_xor(s, off);
  const float Sn = __shfl(s, 0);

  float a1 = -INFINITY, a2 = -INFINITY;
  if (lane < NSPLIT) {
    a1 = W1[row * NSPLIT + lane];
    a2 = W2[row * NSPLIT + lane];
  }
  float As = a1;
#pragma unroll
  for (int off = 1; off < 64; off <<= 1) As = fmaxf(As, __shfl_xor(As, off));
  const float Btot = (5e-6f * Sn + 1e-4f) + 2e-4f * (fabsf(As) + 1.0f);
  const float T = As - 2.0f * Btot;

  float best = -INFINITY;
  int bk = 0x7FFFFFFF;
  if (lane < NSPLIT && a1 >= T) {              // candidate slice winners (~1)
    bk = lane * SPLITK + (int)(__float_as_uint(a1) & 1023u);
    best = exact_score(cb4, spq, bk);
  }
  unsigned long long mflag = __ballot(lane < NSPLIT && a2 >= T);
#pragma unroll 1
  while (mflag) {
    const int sl = __builtin_ctzll(mflag);
    mflag &= mflag - 1;
#pragma unroll 1
    for (int j = 0; j < SPLITK / 64; ++j) {
      const int k = sl * SPLITK + lane * (SPLITK / 64) + j;
      const float sc = exact_score(cb4, spq, k);
      if (sc > best || (sc == best && k < bk)) { best = sc; bk = k; }
    }
  }
  // cross-lane argmax, min-k on ties (numpy first-max)
#pragma unroll
  for (int off = 1; off < 64; off <<= 1) {
    const float ov = __shfl_xor(best, off);
    const int ok = __shfl_xor(bk, off);
    if (ov > best || (ov == best && ok < bk)) { best = ov; bk = ok; }
  }
  if (lane == 0) out2[row] = (float)bk;
  const int tt = row >> 3, cc = row & 7;
  if (lane < DIM) out0[tt * 256 + lane * 8 + cc] = cb[bk * DIM + lane];
  if (blockIdx.x == 0 && threadIdx.x == 0)
    out1[0] = (float)(klsum[0] * (1.4426 * 0.5) / (double)NROWS);
}

extern "C" void kernel_launch(void* const* d_in, const int* in_sizes, int n_in,
                              void* d_out, int out_size, void* d_ws, size_t ws_size,
                              hipStream_t stream) {
  const float* z  = (const float*)d_in[0];
  const float* cb = (const float*)d_in[2];   // d_in[1]=noise unused (STE cancels)

  char* ws = (char*)d_ws;
  float*      M1 = (float*)(ws + WS_M1);
  double* klsum  = (double*)(ws + WS_KL);
  float*      PQ = (float*)(ws + WS_PQ);
  _Float16*   Ah = (_Float16*)(ws + WS_AH);
  _Float16*   Al = (_Float16*)(ws + WS_AL);
  _Float16*   Bh = (_Float16*)(ws + WS_BH);
  _Float16*   Bl = (_Float16*)(ws + WS_BL);
  float*      W1 = (float*)(ws + WS_W1);
  float*      W2 = (float*)(ws + WS_W2);

  float* out0 = (float*)d_out;            // 524288
  float* out1 = out0 + 524288;            // 1
  float* out2 = out1 + 1;                 // 16384

  (void)hipMemsetAsync(ws, 0, 4096, stream);       // M1, klsum = 0
  prep_kernel<<<512, 256, 0, stream>>>(cb, z, Bh, Bl, M1, PQ, Ah, Al, klsum);
  dim3 fgrid(128, NSPLIT);
  filter_kernel<<<fgrid, 128, 0, stream>>>(Ah, Al, Bh, Bl, W1, W2);
  merge_kernel<<<NROWS / 4, 256, 0, stream>>>(PQ, cb, W1, W2, M1, klsum,
                                              out0, out1, out2);
}

// Round 11
// 190.303 us; speedup vs baseline: 3.3967x; 1.2535x over previous
//
#include <hip/hip_runtime.h>
#include <math.h>

// ---------------------------------------------------------------------------
// GaussianQuant — MFMA-filtered argmax, R11.
// score[n,k] = sum_d p*c + q*c^2;  u=[p,q], v=[c,c^2], score = u.v  (K=64)
// fp16 HI-ONLY approx (no lo-split):  |err| <= (2^-10 + eps)*S ~= 1e-3*S,
//   S = sum |p|M1 + |q|M1^2  (rigorous).
// Filter: per (row, c16, split) COLUMN track approx top-1 VALUE only
//   (1 v_max3 per value per 2 tiles; no index pack, no a2, no epilogue).
// Merge: T = A* - 2*Btot, Btot = 1.1e-3*S + 1e-5*|A*| + 1e-3; exact fp32
//   rescan of every column with max >= T (winner's column always included)
//   -> provably sound superset; first-max ties via min-k reduce.
// R11: occupancy fix — hi-only halves A/B regs (≈105 total), (256,4) gives
// 16 waves/CU, whole grid resident; 4 same-split waves/block for L1 reuse.
// ---------------------------------------------------------------------------

typedef _Float16 half8 __attribute__((ext_vector_type(8)));
typedef float f32x4 __attribute__((ext_vector_type(4)));

#define DIM 32
#define NTOK 2048
#define NROWS 16384
#define KSIZE 16384
#define NSPLIT 16
#define SPLITK 1024
#define NTILES 64                      // k-tiles of 16 per split
#define NCOL 256                       // columns per row = NSPLIT*16

// ws layout (bytes); [0,4096) zeroed by memset each launch
#define WS_M1   0                       // 32 float (atomicMax targets)
#define WS_KL   256                     // 1 double (atomicAdd target)
#define WS_PQ   4096                    // 4 MB fp32 [row][64]
#define WS_AH   (WS_PQ + 4194304)       // 2 MB fp16 [row][64]
#define WS_BH   (WS_AH + 2097152)       // 2 MB fp16 [k][64]
#define WS_W1   (WS_BH + 2097152)       // 16 MB fp32 [row][256]  (also absorbs
                                        //  filter's tail over-read past Bh)

// Fused prep: blocks [0,256) pack codebook + per-dim |c| max;
// blocks [256,512) compute p,q + fp16 pack + KL partial sum.
__global__ __launch_bounds__(256) void prep_kernel(const float* __restrict__ cb,
                                                   const float* __restrict__ z,
                                                   _Float16* __restrict__ Bh,
                                                   float* __restrict__ M1,
                                                   float* __restrict__ PQ,
                                                   _Float16* __restrict__ Ah,
                                                   double* __restrict__ klsum) {
  const int w = threadIdx.x >> 6, l = threadIdx.x & 63;
  const int sub = l >> 5, d = l & 31;
  if (blockIdx.x < 256) {
    __shared__ float lm[8][DIM];
    float m = 0.0f;
#pragma unroll
    for (int i = 0; i < 8; ++i) {
      const int k = blockIdx.x * 64 + i * 8 + w * 2 + sub;
      const float c = cb[k * DIM + d];
      Bh[(size_t)k * 64 + d] = (_Float16)c;
      Bh[(size_t)k * 64 + 32 + d] = (_Float16)(c * c);
      m = fmaxf(m, fabsf(c));
    }
    lm[threadIdx.x >> 5][d] = m;
    __syncthreads();
    if (threadIdx.x < DIM) {
      float x = lm[0][threadIdx.x];
#pragma unroll
      for (int i = 1; i < 8; ++i) x = fmaxf(x, lm[i][threadIdx.x]);
      atomicMax((unsigned*)&M1[threadIdx.x], __float_as_uint(x));
    }
  } else {
    const int blk = blockIdx.x - 256;
    double kacc = 0.0;
#pragma unroll 1
    for (int i = 0; i < 8; ++i) {
      const int row = blk * 64 + i * 8 + w * 2 + sub;
      const int t = row >> 3, c = row & 7;
      const float mu = z[t * 512 + d * 8 + c];
      float lv = z[t * 512 + 256 + d * 8 + c];
      lv = fminf(fmaxf(lv, -30.0f), 20.0f);
      const float stdv = expf(0.5f * lv);
      const float iv = 1.0f / (stdv * stdv);   // identical to R2 expression
      const float p = mu * iv;
      const float q = 0.5f * (1.0f - iv);
      PQ[(size_t)row * 64 + d] = p;
      PQ[(size_t)row * 64 + 32 + d] = q;
      Ah[(size_t)row * 64 + d] = (_Float16)p;
      Ah[(size_t)row * 64 + 32 + d] = (_Float16)q;
      kacc += (double)(mu * mu + stdv * stdv - 1.0f - lv);
    }
#pragma unroll
    for (int off = 32; off > 0; off >>= 1) kacc += __shfl_down(kacc, off);
    __shared__ double wsum[4];
    if (l == 0) wsum[w] = kacc;
    __syncthreads();
    if (threadIdx.x == 0)
      atomicAdd(klsum, (wsum[0] + wsum[1]) + (wsum[2] + wsum[3]));
  }
}

// grid (64, 16): x = rowgroup (256 rows), y = split. 4 waves x 64 rows each
// (same split within a block -> L1 reuse of B tiles).
__global__ __launch_bounds__(256, 4) void filter_kernel(const _Float16* __restrict__ Ah,
                                                        const _Float16* __restrict__ Bh,
                                                        float* __restrict__ W1) {
  const int lane = threadIdx.x & 63;
  const int wave = threadIdx.x >> 6;
  const int split = blockIdx.y;
  const int rowbase = blockIdx.x * 256 + wave * 64;   // 4 rowtiles of 16
  const int c16 = lane & 15, quad = lane >> 4;

  half8 uh0[4], uh1[4];
#pragma unroll
  for (int rt = 0; rt < 4; ++rt) {
    const size_t abase = (size_t)(rowbase + rt * 16 + c16) * 64 + quad * 8;
    uh0[rt] = *(const half8*)(Ah + abase);
    uh1[rt] = *(const half8*)(Ah + abase + 32);
  }

  float a1[4][4];
#pragma unroll
  for (int rt = 0; rt < 4; ++rt)
#pragma unroll
    for (int r = 0; r < 4; ++r) a1[rt][r] = -INFINITY;

  const f32x4 fzero = {0.f, 0.f, 0.f, 0.f};
  const _Float16* pbh = Bh + (size_t)(split * SPLITK + c16) * 64 + quad * 8;

  // software pipeline: pair (x,y) in regs, prefetch next pair each iter
  half8 xh0 = *(const half8*)(pbh);
  half8 xh1 = *(const half8*)(pbh + 32);
  half8 yh0 = *(const half8*)(pbh + 1024);
  half8 yh1 = *(const half8*)(pbh + 1024 + 32);
#pragma unroll 1
  for (int t = 0; t < NTILES; t += 2) {
    // prefetch tiles t+2, t+3 (tail over-reads ~4KB into W1 region: harmless)
    const _Float16* pn = pbh + (size_t)(t + 2) * 1024;
    const half8 nxh0 = *(const half8*)(pn);
    const half8 nxh1 = *(const half8*)(pn + 32);
    const half8 nyh0 = *(const half8*)(pn + 1024);
    const half8 nyh1 = *(const half8*)(pn + 1024 + 32);
#pragma unroll
    for (int rt = 0; rt < 4; ++rt) {
      f32x4 h0 = __builtin_amdgcn_mfma_f32_16x16x32_f16(uh0[rt], xh0, fzero, 0, 0, 0);
      h0 = __builtin_amdgcn_mfma_f32_16x16x32_f16(uh1[rt], xh1, h0, 0, 0, 0);
      f32x4 h1 = __builtin_amdgcn_mfma_f32_16x16x32_f16(uh0[rt], yh0, fzero, 0, 0, 0);
      h1 = __builtin_amdgcn_mfma_f32_16x16x32_f16(uh1[rt], yh1, h1, 0, 0, 0);
#pragma unroll
      for (int r = 0; r < 4; ++r)
        a1[rt][r] = fmaxf(fmaxf(h0[r], h1[r]), a1[rt][r]);   // v_max3
    }
    xh0 = nxh0; xh1 = nxh1; yh0 = nyh0; yh1 = nyh1;
  }

  // store per-column approx maxima: col = split*16 + c16
#pragma unroll
  for (int rt = 0; rt < 4; ++rt)
#pragma unroll
    for (int r = 0; r < 4; ++r) {
      const int row_r = rowbase + rt * 16 + quad * 4 + r;   // C: row=quad*4+reg
      W1[(size_t)row_r * NCOL + split * 16 + c16] = a1[rt][r];
    }
}

// exact fp32 score, p/q broadcast from LDS (identical formula to R2)
__device__ __forceinline__ float exact_score(const float4* __restrict__ cb4,
                                             const float4* __restrict__ spq,
                                             int k) {
  float s0 = 0.0f, s1 = 0.0f, s2 = 0.0f, s3 = 0.0f;
#pragma unroll
  for (int m = 0; m < 8; ++m) {
    const float4 cv = cb4[k * 8 + m];
    const float4 pv = spq[m];        // p[4m..4m+3]
    const float4 qv = spq[8 + m];    // q[4m..4m+3]
    s0 = fmaf(cv.x, fmaf(qv.x, cv.x, pv.x), s0);
    s1 = fmaf(cv.y, fmaf(qv.y, cv.y, pv.y), s1);
    s2 = fmaf(cv.z, fmaf(qv.z, cv.z, pv.z), s2);
    s3 = fmaf(cv.w, fmaf(qv.w, cv.w, pv.w), s3);
  }
  return (s0 + s1) + (s2 + s3);
}

// 1 wave per row; 4 rows per block. Bn + column rescans + out2 + gather +
// out1. A column rescan = 1 exact score per lane (lane = tile index).
__global__ __launch_bounds__(256, 4) void merge_kernel(const float* __restrict__ PQ,
                                                       const float* __restrict__ cb,
                                                       const float* __restrict__ W1,
                                                       const float* __restrict__ M1,
                                                       const double* __restrict__ klsum,
                                                       float* __restrict__ out0,
                                                       float* __restrict__ out1,
                                                       float* __restrict__ out2) {
  __shared__ float4 spq_s[4][16];
  const int lane = threadIdx.x & 63;
  const int wave = threadIdx.x >> 6;
  const int row = blockIdx.x * 4 + wave;

  if (lane < 16)
    spq_s[wave][lane] = ((const float4*)(PQ + (size_t)row * 64))[lane];
  __syncthreads();
  const float4* spq = spq_s[wave];
  const float4* __restrict__ cb4 = (const float4*)cb;

  // per-row rigorous bound S = sum |p|M1 + |q|M1^2
  float s = 0.0f;
  if (lane < DIM) {
    const float m1 = M1[lane];
    const float pd = ((const float*)spq)[lane];
    const float qd = ((const float*)spq)[32 + lane];
    s = fabsf(pd) * m1 + fabsf(qd) * m1 * m1;
  }
#pragma unroll
  for (int off = 1; off < 32; off <<= 1) s += __shfl_xor(s, off);
  const float Sn = __shfl(s, 0);

  // load 256 column maxima (4 per lane), find A*
  float w[4];
#pragma unroll
  for (int i = 0; i < 4; ++i) w[i] = W1[(size_t)row * NCOL + i * 64 + lane];
  float As = fmaxf(fmaxf(w[0], w[1]), fmaxf(w[2], w[3]));
#pragma unroll
  for (int off = 1; off < 64; off <<= 1) As = fmaxf(As, __shfl_xor(As, off));
  const float Btot = 1.1e-3f * Sn + 1e-5f * fabsf(As) + 1e-3f;
  const float T = As - 2.0f * Btot;

  float best = -INFINITY;
  int bk = 0x7FFFFFFF;
#pragma unroll 1
  for (int i = 0; i < 4; ++i) {
    unsigned long long m = __ballot(w[i] >= T);
    while (m) {
      const int e = __builtin_ctzll(m);
      m &= m - 1;
      const int col = i * 64 + e;
      const int k = (col >> 4) * SPLITK + lane * 16 + (col & 15);
      const float sc = exact_score(cb4, spq, k);
      if (sc > best || (sc == best && k < bk)) { best = sc; bk = k; }
    }
  }
  // cross-lane argmax, min-k on ties (numpy first-max)
#pragma unroll
  for (int off = 1; off < 64; off <<= 1) {
    const float ov = __shfl_xor(best, off);
    const int ok = __shfl_xor(bk, off);
    if (ov > best || (ov == best && ok < bk)) { best = ov; bk = ok; }
  }
  if (lane == 0) out2[row] = (float)bk;
  const int tt = row >> 3, cc = row & 7;
  if (lane < DIM) out0[tt * 256 + lane * 8 + cc] = cb[bk * DIM + lane];
  if (blockIdx.x == 0 && threadIdx.x == 0)
    out1[0] = (float)(klsum[0] * (1.4426 * 0.5) / (double)NROWS);
}

extern "C" void kernel_launch(void* const* d_in, const int* in_sizes, int n_in,
                              void* d_out, int out_size, void* d_ws, size_t ws_size,
                              hipStream_t stream) {
  const float* z  = (const float*)d_in[0];
  const float* cb = (const float*)d_in[2];   // d_in[1]=noise unused (STE cancels)

  char* ws = (char*)d_ws;
  float*      M1 = (float*)(ws + WS_M1);
  double* klsum  = (double*)(ws + WS_KL);
  float*      PQ = (float*)(ws + WS_PQ);
  _Float16*   Ah = (_Float16*)(ws + WS_AH);
  _Float16*   Bh = (_Float16*)(ws + WS_BH);
  float*      W1 = (float*)(ws + WS_W1);

  float* out0 = (float*)d_out;            // 524288
  float* out1 = out0 + 524288;            // 1
  float* out2 = out1 + 1;                 // 16384

  (void)hipMemsetAsync(ws, 0, 4096, stream);       // M1, klsum = 0
  prep_kernel<<<512, 256, 0, stream>>>(cb, z, Bh, M1, PQ, Ah, klsum);
  dim3 fgrid(64, NSPLIT);
  filter_kernel<<<fgrid, 256, 0, stream>>>(Ah, Bh, W1);
  merge_kernel<<<NROWS / 4, 256, 0, stream>>>(PQ, cb, W1, M1, klsum,
                                              out0, out1, out2);
}

// Round 12
// 188.357 us; speedup vs baseline: 3.4318x; 1.0103x over previous
//
#include <hip/hip_runtime.h>
#include <math.h>

// ---------------------------------------------------------------------------
// GaussianQuant — MFMA-filtered argmax, R12.
// score[n,k] = sum_d p*c + q*c^2;  u=[p,q], v=[c,c^2], score = u.v  (K=64)
// fp16 HI-ONLY approx: |err| <= 1.05e-3*S (rigorous; incl. MFMA accum),
//   S = sum |p|M1 + |q|M1^2.
// Filter: per (row, column=(split,c16)) approx top-1 with 6-bit TILE INDEX
//   packed into the value's low mantissa bits (and_or + max3 per value).
// Merge (two-phase, sound):
//   A* = max packed col-max. Btot = 1.05e-3*S + 2e-5*(|A*|+1) + 1e-3.
//   Phase A: exact-rescore stored winners of cols >= A* - 2*Btot -> E*.
//   Phase B: full 64-k rescan of every col with W1 + Btot >= E*  (any k in
//   col c has true <= W1[c]+Btot; pruned cols are strictly below E*, so the
//   true argmax and all first-max ties survive). Min-k tie rule throughout.
// R12: filter depth-2 pair pipeline (L2 latency was the R11 limiter) at
// (256,3); merge phase-split kills the R11 rescan blowup; prep 1024 blocks.
// ---------------------------------------------------------------------------

typedef _Float16 half8 __attribute__((ext_vector_type(8)));
typedef float f32x4 __attribute__((ext_vector_type(4)));

#define DIM 32
#define NTOK 2048
#define NROWS 16384
#define KSIZE 16384
#define NSPLIT 16
#define SPLITK 1024
#define NTILES 64                      // k-tiles of 16 per split
#define NCOL 256                       // columns per row = NSPLIT*16
#define PMASK 0xFFFFFFC0u              // clear low 6 mantissa bits (tile idx)

// ws layout (bytes); [0,4096) zeroed by memset each launch
#define WS_M1   0                       // 32 float (atomicMax targets)
#define WS_KL   256                     // 1 double (atomicAdd target)
#define WS_PQ   4096                    // 4 MB fp32 [row][64]
#define WS_AH   (WS_PQ + 4194304)       // 2 MB fp16 [row][64]
#define WS_BH   (WS_AH + 2097152)       // 2 MB fp16 [k][64]
#define WS_W1   (WS_BH + 2097152)       // 16 MB fp32 [row][256] packed
                                        //  (also absorbs filter tail over-read)

// Fused prep, 1024 blocks: [0,512) pack codebook + per-dim |c| max;
// [512,1024) compute p,q + fp16 pack + KL partial sum.
__global__ __launch_bounds__(256) void prep_kernel(const float* __restrict__ cb,
                                                   const float* __restrict__ z,
                                                   _Float16* __restrict__ Bh,
                                                   float* __restrict__ M1,
                                                   float* __restrict__ PQ,
                                                   _Float16* __restrict__ Ah,
                                                   double* __restrict__ klsum) {
  const int w = threadIdx.x >> 6, l = threadIdx.x & 63;
  const int sub = l >> 5, d = l & 31;
  if (blockIdx.x < 512) {
    __shared__ float lm[8][DIM];
    float m = 0.0f;
#pragma unroll
    for (int i = 0; i < 4; ++i) {
      const int k = blockIdx.x * 32 + i * 8 + w * 2 + sub;
      const float c = cb[k * DIM + d];
      Bh[(size_t)k * 64 + d] = (_Float16)c;
      Bh[(size_t)k * 64 + 32 + d] = (_Float16)(c * c);
      m = fmaxf(m, fabsf(c));
    }
    lm[threadIdx.x >> 5][d] = m;
    __syncthreads();
    if (threadIdx.x < DIM) {
      float x = lm[0][threadIdx.x];
#pragma unroll
      for (int i = 1; i < 8; ++i) x = fmaxf(x, lm[i][threadIdx.x]);
      atomicMax((unsigned*)&M1[threadIdx.x], __float_as_uint(x));
    }
  } else {
    const int blk = blockIdx.x - 512;
    double kacc = 0.0;
#pragma unroll 1
    for (int i = 0; i < 4; ++i) {
      const int row = blk * 32 + i * 8 + w * 2 + sub;
      const int t = row >> 3, c = row & 7;
      const float mu = z[t * 512 + d * 8 + c];
      float lv = z[t * 512 + 256 + d * 8 + c];
      lv = fminf(fmaxf(lv, -30.0f), 20.0f);
      const float stdv = expf(0.5f * lv);
      const float iv = 1.0f / (stdv * stdv);   // identical to R2 expression
      const float p = mu * iv;
      const float q = 0.5f * (1.0f - iv);
      PQ[(size_t)row * 64 + d] = p;
      PQ[(size_t)row * 64 + 32 + d] = q;
      Ah[(size_t)row * 64 + d] = (_Float16)p;
      Ah[(size_t)row * 64 + 32 + d] = (_Float16)q;
      kacc += (double)(mu * mu + stdv * stdv - 1.0f - lv);
    }
#pragma unroll
    for (int off = 32; off > 0; off >>= 1) kacc += __shfl_down(kacc, off);
    __shared__ double wsum[4];
    if (l == 0) wsum[w] = kacc;
    __syncthreads();
    if (threadIdx.x == 0)
      atomicAdd(klsum, (wsum[0] + wsum[1]) + (wsum[2] + wsum[3]));
  }
}

// compute one PAIR of tiles (ta, tb) held in 4 half8 buffers
#define FPAIR(B0a, B1a, B0b, B1b, TA, TB)                                     \
  {                                                                           \
    _Pragma("unroll")                                                         \
    for (int rt = 0; rt < 4; ++rt) {                                          \
      f32x4 h0 = __builtin_amdgcn_mfma_f32_16x16x32_f16(uh0[rt], B0a, fzero, 0, 0, 0); \
      h0 = __builtin_amdgcn_mfma_f32_16x16x32_f16(uh1[rt], B1a, h0, 0, 0, 0); \
      f32x4 h1 = __builtin_amdgcn_mfma_f32_16x16x32_f16(uh0[rt], B0b, fzero, 0, 0, 0); \
      h1 = __builtin_amdgcn_mfma_f32_16x16x32_f16(uh1[rt], B1b, h1, 0, 0, 0); \
      _Pragma("unroll")                                                       \
      for (int r = 0; r < 4; ++r) {                                           \
        const float pa = __uint_as_float((__float_as_uint(h0[r]) & PMASK) | (TA)); \
        const float pb = __uint_as_float((__float_as_uint(h1[r]) & PMASK) | (TB)); \
        a1[rt][r] = fmaxf(fmaxf(pa, pb), a1[rt][r]);   /* v_max3 */           \
      }                                                                       \
    }                                                                         \
  }

// grid (64, 16): x = rowgroup (256 rows), y = split. 4 waves x 64 rows each
// (same split within a block -> L1 reuse of B tiles).
__global__ __launch_bounds__(256, 3) void filter_kernel(const _Float16* __restrict__ Ah,
                                                        const _Float16* __restrict__ Bh,
                                                        float* __restrict__ W1) {
  const int lane = threadIdx.x & 63;
  const int wave = threadIdx.x >> 6;
  const int split = blockIdx.y;
  const int rowbase = blockIdx.x * 256 + wave * 64;   // 4 rowtiles of 16
  const int c16 = lane & 15, quad = lane >> 4;

  half8 uh0[4], uh1[4];
#pragma unroll
  for (int rt = 0; rt < 4; ++rt) {
    const size_t abase = (size_t)(rowbase + rt * 16 + c16) * 64 + quad * 8;
    uh0[rt] = *(const half8*)(Ah + abase);
    uh1[rt] = *(const half8*)(Ah + abase + 32);
  }

  float a1[4][4];
#pragma unroll
  for (int rt = 0; rt < 4; ++rt)
#pragma unroll
    for (int r = 0; r < 4; ++r) a1[rt][r] = -INFINITY;

  const f32x4 fzero = {0.f, 0.f, 0.f, 0.f};
  const _Float16* pbh = Bh + (size_t)(split * SPLITK + c16) * 64 + quad * 8;

  // depth-2 pair pipeline: pairs p, p+1 resident; p+2, p+3 prefetched.
  // tail over-reads up to ~8KB past Bh into W1 region: harmless.
#define LDPAIR(dst0a, dst1a, dst0b, dst1b, P)                    \
  {                                                              \
    const _Float16* _s = pbh + (size_t)(P) * 2048;               \
    dst0a = *(const half8*)(_s);                                 \
    dst1a = *(const half8*)(_s + 32);                            \
    dst0b = *(const half8*)(_s + 1024);                          \
    dst1b = *(const half8*)(_s + 1024 + 32);                     \
  }
  half8 p0a0, p0a1, p0b0, p0b1, p1a0, p1a1, p1b0, p1b1;
  LDPAIR(p0a0, p0a1, p0b0, p0b1, 0);
  LDPAIR(p1a0, p1a1, p1b0, p1b1, 1);
#pragma unroll 1
  for (int p = 0; p < 32; p += 2) {
    half8 q0a0, q0a1, q0b0, q0b1, q1a0, q1a1, q1b0, q1b1;
    LDPAIR(q0a0, q0a1, q0b0, q0b1, p + 2);
    FPAIR(p0a0, p0a1, p0b0, p0b1, (unsigned)(2 * p), (unsigned)(2 * p + 1));
    LDPAIR(q1a0, q1a1, q1b0, q1b1, p + 3);
    FPAIR(p1a0, p1a1, p1b0, p1b1, (unsigned)(2 * p + 2), (unsigned)(2 * p + 3));
    p0a0 = q0a0; p0a1 = q0a1; p0b0 = q0b0; p0b1 = q0b1;
    p1a0 = q1a0; p1a1 = q1a1; p1b0 = q1b0; p1b1 = q1b1;
  }

  // store per-column packed (value | tile) maxima: col = split*16 + c16
#pragma unroll
  for (int rt = 0; rt < 4; ++rt)
#pragma unroll
    for (int r = 0; r < 4; ++r) {
      const int row_r = rowbase + rt * 16 + quad * 4 + r;   // C: row=quad*4+reg
      W1[(size_t)row_r * NCOL + split * 16 + c16] = a1[rt][r];
    }
}

// exact fp32 score, p/q broadcast from LDS (identical formula to R2)
__device__ __forceinline__ float exact_score(const float4* __restrict__ cb4,
                                             const float4* __restrict__ spq,
                                             int k) {
  float s0 = 0.0f, s1 = 0.0f, s2 = 0.0f, s3 = 0.0f;
#pragma unroll
  for (int m = 0; m < 8; ++m) {
    const float4 cv = cb4[k * 8 + m];
    const float4 pv = spq[m];        // p[4m..4m+3]
    const float4 qv = spq[8 + m];    // q[4m..4m+3]
    s0 = fmaf(cv.x, fmaf(qv.x, cv.x, pv.x), s0);
    s1 = fmaf(cv.y, fmaf(qv.y, cv.y, pv.y), s1);
    s2 = fmaf(cv.z, fmaf(qv.z, cv.z, pv.z), s2);
    s3 = fmaf(cv.w, fmaf(qv.w, cv.w, pv.w), s3);
  }
  return (s0 + s1) + (s2 + s3);
}

// 1 wave per row; 4 rows per block. Two-phase candidate rescoring + out2 +
// gather (out0) + out1 (kl scalar).
__global__ __launch_bounds__(256, 4) void merge_kernel(const float* __restrict__ PQ,
                                                       const float* __restrict__ cb,
                                                       const float* __restrict__ W1,
                                                       const float* __restrict__ M1,
                                                       const double* __restrict__ klsum,
                                                       float* __restrict__ out0,
                                                       float* __restrict__ out1,
                                                       float* __restrict__ out2) {
  __shared__ float4 spq_s[4][16];
  const int lane = threadIdx.x & 63;
  const int wave = threadIdx.x >> 6;
  const int row = blockIdx.x * 4 + wave;

  if (lane < 16)
    spq_s[wave][lane] = ((const float4*)(PQ + (size_t)row * 64))[lane];
  __syncthreads();
  const float4* spq = spq_s[wave];
  const float4* __restrict__ cb4 = (const float4*)cb;

  // per-row rigorous bound S = sum |p|M1 + |q|M1^2
  float s = 0.0f;
  if (lane < DIM) {
    const float m1 = M1[lane];
    const float pd = ((const float*)spq)[lane];
    const float qd = ((const float*)spq)[32 + lane];
    s = fabsf(pd) * m1 + fabsf(qd) * m1 * m1;
  }
#pragma unroll
  for (int off = 1; off < 32; off <<= 1) s += __shfl_xor(s, off);
  const float Sn = __shfl(s, 0);

  // load 256 packed column maxima (4 per lane), find A*
  float w[4];
#pragma unroll
  for (int i = 0; i < 4; ++i) w[i] = W1[(size_t)row * NCOL + i * 64 + lane];
  float As = fmaxf(fmaxf(w[0], w[1]), fmaxf(w[2], w[3]));
#pragma unroll
  for (int off = 1; off < 64; off <<= 1) As = fmaxf(As, __shfl_xor(As, off));
  const float Btot = 1.05e-3f * Sn + 2e-5f * (fabsf(As) + 1.0f) + 1e-3f;

  // ---- phase A: exact-rescore stored winners of candidate columns ----
  const float TA = As - 2.0f * Btot;
  float best = -INFINITY;
  int bk = 0x7FFFFFFF;
#pragma unroll
  for (int i = 0; i < 4; ++i) {
    if (w[i] >= TA) {
      const int col = i * 64 + lane;
      const int tc = (int)(__float_as_uint(w[i]) & 63u);
      const int k = (col >> 4) * SPLITK + tc * 16 + (col & 15);
      const float sc = exact_score(cb4, spq, k);
      if (sc > best || (sc == best && k < bk)) { best = sc; bk = k; }
    }
  }
#pragma unroll
  for (int off = 1; off < 64; off <<= 1) {
    const float ov = __shfl_xor(best, off);
    const int ok = __shfl_xor(bk, off);
    if (ov > best || (ov == best && ok < bk)) { best = ov; bk = ok; }
  }
  const float Estar = best;   // exact score of some real k; all lanes agree

  // ---- phase B: full rescan of columns that could still contain the max ----
#pragma unroll 1
  for (int i = 0; i < 4; ++i) {
    unsigned long long m = __ballot(w[i] + Btot >= Estar);
    while (m) {
      const int e = __builtin_ctzll(m);
      m &= m - 1;
      const int col = i * 64 + e;
      const int k = (col >> 4) * SPLITK + lane * 16 + (col & 15);
      const float sc = exact_score(cb4, spq, k);
      if (sc > best || (sc == best && k < bk)) { best = sc; bk = k; }
    }
  }
  // final cross-lane argmax, min-k on ties (numpy first-max)
#pragma unroll
  for (int off = 1; off < 64; off <<= 1) {
    const float ov = __shfl_xor(best, off);
    const int ok = __shfl_xor(bk, off);
    if (ov > best || (ov == best && ok < bk)) { best = ov; bk = ok; }
  }
  if (lane == 0) out2[row] = (float)bk;
  const int tt = row >> 3, cc = row & 7;
  if (lane < DIM) out0[tt * 256 + lane * 8 + cc] = cb[bk * DIM + lane];
  if (blockIdx.x == 0 && threadIdx.x == 0)
    out1[0] = (float)(klsum[0] * (1.4426 * 0.5) / (double)NROWS);
}

extern "C" void kernel_launch(void* const* d_in, const int* in_sizes, int n_in,
                              void* d_out, int out_size, void* d_ws, size_t ws_size,
                              hipStream_t stream) {
  const float* z  = (const float*)d_in[0];
  const float* cb = (const float*)d_in[2];   // d_in[1]=noise unused (STE cancels)

  char* ws = (char*)d_ws;
  float*      M1 = (float*)(ws + WS_M1);
  double* klsum  = (double*)(ws + WS_KL);
  float*      PQ = (float*)(ws + WS_PQ);
  _Float16*   Ah = (_Float16*)(ws + WS_AH);
  _Float16*   Bh = (_Float16*)(ws + WS_BH);
  float*      W1 = (float*)(ws + WS_W1);

  float* out0 = (float*)d_out;            // 524288
  float* out1 = out0 + 524288;            // 1
  float* out2 = out1 + 1;                 // 16384

  (void)hipMemsetAsync(ws, 0, 4096, stream);       // M1, klsum = 0
  prep_kernel<<<1024, 256, 0, stream>>>(cb, z, Bh, M1, PQ, Ah, klsum);
  dim3 fgrid(64, NSPLIT);
  filter_kernel<<<fgrid, 256, 0, stream>>>(Ah, Bh, W1);
  merge_kernel<<<NROWS / 4, 256, 0, stream>>>(PQ, cb, W1, M1, klsum,
                                              out0, out1, out2);
}

// Round 13
// 162.143 us; speedup vs baseline: 3.9866x; 1.1617x over previous
//
#include <hip/hip_runtime.h>
#include <math.h>

// ---------------------------------------------------------------------------
// GaussianQuant — MFMA-filtered argmax, R13.
// score[n,k] = sum_d p*c + q*c^2;  u=[p,q], v=[c,c^2], score = u.v  (K=64)
// fp16 HI-ONLY approx: |err| <= 1.05e-3*S (rigorous), S = sum |p|M1+|q|M1^2.
// Filter: per (row, column=(split,c16)) approx top-1 with 6-bit TILE INDEX
//   packed into low mantissa bits (and_or x2 + max3 per value-pair).
// Merge (two-phase, sound): A* = max col-max; Btot = 1.05e-3*S +
//   2e-5*(|A*|+1) + 1e-3. Phase A: exact-rescore stored winners of cols >=
//   A* - 2*Btot -> E*. Phase B: full rescan of cols with W1 + Btot >= E*.
// R13: filter stages B through double-buffered LDS shared by the block's 4
// waves (4x L2-traffic cut; ds 120cyc vs L2 300cyc). Bh is PRE-SWIZZLED in
// prep (slot ^= k&7) so staging is a linear copy and ds_read_b128 is
// conflict-free with zero extra registers (R9's spill cause eliminated).
// ---------------------------------------------------------------------------

typedef _Float16 half8 __attribute__((ext_vector_type(8)));
typedef float f32x4 __attribute__((ext_vector_type(4)));

#define DIM 32
#define NTOK 2048
#define NROWS 16384
#define KSIZE 16384
#define NSPLIT 16
#define SPLITK 1024
#define NCOL 256                       // columns per row = NSPLIT*16
#define PMASK 0xFFFFFFC0u              // clear low 6 mantissa bits (tile idx)

// ws layout (bytes); [0,4096) zeroed by memset each launch
#define WS_M1   0                       // 32 float (atomicMax targets)
#define WS_KL   256                     // 1 double (atomicAdd target)
#define WS_PQ   4096                    // 4 MB fp32 [row][64]
#define WS_AH   (WS_PQ + 4194304)       // 2 MB fp16 [row][64]
#define WS_BH   (WS_AH + 2097152)       // 2 MB fp16 [k][64] PRE-SWIZZLED
#define WS_W1   (WS_BH + 2097152)       // 16 MB fp32 [row][256] packed

// Fused prep, 1024 blocks: [0,512) pack codebook (swizzled) + per-dim max;
// [512,1024) compute p,q + fp16 pack + KL partial sum.
__global__ __launch_bounds__(256) void prep_kernel(const float* __restrict__ cb,
                                                   const float* __restrict__ z,
                                                   _Float16* __restrict__ Bh,
                                                   float* __restrict__ M1,
                                                   float* __restrict__ PQ,
                                                   _Float16* __restrict__ Ah,
                                                   double* __restrict__ klsum) {
  const int w = threadIdx.x >> 6, l = threadIdx.x & 63;
  const int sub = l >> 5, d = l & 31;
  if (blockIdx.x < 512) {
    __shared__ float lm[8][DIM];
    float m = 0.0f;
#pragma unroll
    for (int i = 0; i < 4; ++i) {
      const int k = blockIdx.x * 32 + i * 8 + w * 2 + sub;
      const float c = cb[k * DIM + d];
      // swizzled slot layout: logical slot s (8 halfs) stored at s ^ (k&7)
      const int key = k & 7;
      const int sc = (d >> 3) ^ key;          // c-part: logical slot d>>3
      const int sq = (4 + (d >> 3)) ^ key;    // c^2-part: logical slot 4+d>>3
      Bh[(size_t)k * 64 + sc * 8 + (d & 7)] = (_Float16)c;
      Bh[(size_t)k * 64 + sq * 8 + (d & 7)] = (_Float16)(c * c);
      m = fmaxf(m, fabsf(c));
    }
    lm[threadIdx.x >> 5][d] = m;
    __syncthreads();
    if (threadIdx.x < DIM) {
      float x = lm[0][threadIdx.x];
#pragma unroll
      for (int i = 1; i < 8; ++i) x = fmaxf(x, lm[i][threadIdx.x]);
      atomicMax((unsigned*)&M1[threadIdx.x], __float_as_uint(x));
    }
  } else {
    const int blk = blockIdx.x - 512;
    double kacc = 0.0;
#pragma unroll 1
    for (int i = 0; i < 4; ++i) {
      const int row = blk * 32 + i * 8 + w * 2 + sub;
      const int t = row >> 3, c = row & 7;
      const float mu = z[t * 512 + d * 8 + c];
      float lv = z[t * 512 + 256 + d * 8 + c];
      lv = fminf(fmaxf(lv, -30.0f), 20.0f);
      const float stdv = expf(0.5f * lv);
      const float iv = 1.0f / (stdv * stdv);   // identical to R2 expression
      const float p = mu * iv;
      const float q = 0.5f * (1.0f - iv);
      PQ[(size_t)row * 64 + d] = p;
      PQ[(size_t)row * 64 + 32 + d] = q;
      Ah[(size_t)row * 64 + d] = (_Float16)p;
      Ah[(size_t)row * 64 + 32 + d] = (_Float16)q;
      kacc += (double)(mu * mu + stdv * stdv - 1.0f - lv);
    }
#pragma unroll
    for (int off = 32; off > 0; off >>= 1) kacc += __shfl_down(kacc, off);
    __shared__ double wsum[4];
    if (l == 0) wsum[w] = kacc;
    __syncthreads();
    if (threadIdx.x == 0)
      atomicAdd(klsum, (wsum[0] + wsum[1]) + (wsum[2] + wsum[3]));
  }
}

// grid (64, 16): x = rowgroup (256 rows), y = split. 4 waves x 64 rows each.
// B staged through 2 x 16 KB LDS buffers (8 tiles/chunk), shared by 4 waves.
__global__ __launch_bounds__(256, 4) void filter_kernel(const _Float16* __restrict__ Ah,
                                                        const _Float16* __restrict__ Bh,
                                                        float* __restrict__ W1) {
  __shared__ _Float16 sB[2][8192];   // 2 x 16 KB
  const int tid = threadIdx.x;
  const int lane = tid & 63;
  const int wave = tid >> 6;
  const int split = blockIdx.y;
  const int rowbase = blockIdx.x * 256 + wave * 64;   // 4 rowtiles of 16
  const int c16 = lane & 15, quad = lane >> 4;

  half8 uh0[4], uh1[4];
#pragma unroll
  for (int rt = 0; rt < 4; ++rt) {
    const size_t abase = (size_t)(rowbase + rt * 16 + c16) * 64 + quad * 8;
    uh0[rt] = *(const half8*)(Ah + abase);
    uh1[rt] = *(const half8*)(Ah + abase + 32);
  }

  float a1[4][4];
#pragma unroll
  for (int rt = 0; rt < 4; ++rt)
#pragma unroll
    for (int r = 0; r < 4; ++r) a1[rt][r] = -INFINITY;

  const f32x4 fzero = {0.f, 0.f, 0.f, 0.f};
  const _Float16* gB = Bh + (size_t)split * SPLITK * 64;  // 128 KB region

  // stage chunk 0 (each thread: 4 x 16B, coalesced; linear copy)
  float4 st[4];
#pragma unroll
  for (int j = 0; j < 4; ++j) st[j] = *(const float4*)(gB + j * 2048 + tid * 8);
#pragma unroll
  for (int j = 0; j < 4; ++j) *(float4*)(&sB[0][j * 2048 + tid * 8]) = st[j];
  __syncthreads();

  // swizzled read offsets (halfs): row c16, physical slot = logical ^ (c16&7)
  const int key = c16 & 7;
  const int rs0h = c16 * 64 + (quad ^ key) * 8;         // p-part (slots 0-3)
  const int rs1h = c16 * 64 + (((quad + 4) ^ key)) * 8; // q-part (slots 4-7)

#pragma unroll 1
  for (int ch = 0; ch < 8; ++ch) {
    if (ch < 7) {
      const _Float16* src = gB + (size_t)(ch + 1) * 8192;
#pragma unroll
      for (int j = 0; j < 4; ++j) st[j] = *(const float4*)(src + j * 2048 + tid * 8);
    }
    const _Float16* buf = sB[ch & 1];
#pragma unroll 1
    for (int tp = 0; tp < 4; ++tp) {          // 4 tile-pairs per chunk
      const _Float16* b0 = buf + (2 * tp) * 1024;
      const _Float16* b1 = buf + (2 * tp + 1) * 1024;
      const half8 x0 = *(const half8*)(b0 + rs0h);
      const half8 x1 = *(const half8*)(b0 + rs1h);
      const half8 y0 = *(const half8*)(b1 + rs0h);
      const half8 y1 = *(const half8*)(b1 + rs1h);
      const unsigned ta = (unsigned)(ch * 8 + 2 * tp);
      const unsigned tb = ta + 1;
#pragma unroll
      for (int rt = 0; rt < 4; ++rt) {
        f32x4 h0 = __builtin_amdgcn_mfma_f32_16x16x32_f16(uh0[rt], x0, fzero, 0, 0, 0);
        h0 = __builtin_amdgcn_mfma_f32_16x16x32_f16(uh1[rt], x1, h0, 0, 0, 0);
        f32x4 h1 = __builtin_amdgcn_mfma_f32_16x16x32_f16(uh0[rt], y0, fzero, 0, 0, 0);
        h1 = __builtin_amdgcn_mfma_f32_16x16x32_f16(uh1[rt], y1, h1, 0, 0, 0);
#pragma unroll
        for (int r = 0; r < 4; ++r) {
          const float pa = __uint_as_float((__float_as_uint(h0[r]) & PMASK) | ta);
          const float pb = __uint_as_float((__float_as_uint(h1[r]) & PMASK) | tb);
          a1[rt][r] = fmaxf(fmaxf(pa, pb), a1[rt][r]);   // v_max3
        }
      }
    }
    __syncthreads();
    if (ch < 7) {
      _Float16* dst = sB[(ch + 1) & 1];
#pragma unroll
      for (int j = 0; j < 4; ++j) *(float4*)(dst + j * 2048 + tid * 8) = st[j];
    }
    __syncthreads();
  }

  // store per-column packed (value | tile) maxima: col = split*16 + c16
#pragma unroll
  for (int rt = 0; rt < 4; ++rt)
#pragma unroll
    for (int r = 0; r < 4; ++r) {
      const int row_r = rowbase + rt * 16 + quad * 4 + r;   // C: row=quad*4+reg
      W1[(size_t)row_r * NCOL + split * 16 + c16] = a1[rt][r];
    }
}

// exact fp32 score, p/q broadcast from LDS (identical formula to R2)
__device__ __forceinline__ float exact_score(const float4* __restrict__ cb4,
                                             const float4* __restrict__ spq,
                                             int k) {
  float s0 = 0.0f, s1 = 0.0f, s2 = 0.0f, s3 = 0.0f;
#pragma unroll
  for (int m = 0; m < 8; ++m) {
    const float4 cv = cb4[k * 8 + m];
    const float4 pv = spq[m];        // p[4m..4m+3]
    const float4 qv = spq[8 + m];    // q[4m..4m+3]
    s0 = fmaf(cv.x, fmaf(qv.x, cv.x, pv.x), s0);
    s1 = fmaf(cv.y, fmaf(qv.y, cv.y, pv.y), s1);
    s2 = fmaf(cv.z, fmaf(qv.z, cv.z, pv.z), s2);
    s3 = fmaf(cv.w, fmaf(qv.w, cv.w, pv.w), s3);
  }
  return (s0 + s1) + (s2 + s3);
}

// 1 wave per row; 4 rows per block. Two-phase candidate rescoring + out2 +
// gather (out0) + out1 (kl scalar).
__global__ __launch_bounds__(256, 4) void merge_kernel(const float* __restrict__ PQ,
                                                       const float* __restrict__ cb,
                                                       const float* __restrict__ W1,
                                                       const float* __restrict__ M1,
                                                       const double* __restrict__ klsum,
                                                       float* __restrict__ out0,
                                                       float* __restrict__ out1,
                                                       float* __restrict__ out2) {
  __shared__ float4 spq_s[4][16];
  const int lane = threadIdx.x & 63;
  const int wave = threadIdx.x >> 6;
  const int row = blockIdx.x * 4 + wave;

  if (lane < 16)
    spq_s[wave][lane] = ((const float4*)(PQ + (size_t)row * 64))[lane];
  __syncthreads();
  const float4* spq = spq_s[wave];
  const float4* __restrict__ cb4 = (const float4*)cb;

  // per-row rigorous bound S = sum |p|M1 + |q|M1^2
  float s = 0.0f;
  if (lane < DIM) {
    const float m1 = M1[lane];
    const float pd = ((const float*)spq)[lane];
    const float qd = ((const float*)spq)[32 + lane];
    s = fabsf(pd) * m1 + fabsf(qd) * m1 * m1;
  }
#pragma unroll
  for (int off = 1; off < 32; off <<= 1) s += __shfl_xor(s, off);
  const float Sn = __shfl(s, 0);

  // load 256 packed column maxima (4 per lane), find A*
  float w[4];
#pragma unroll
  for (int i = 0; i < 4; ++i) w[i] = W1[(size_t)row * NCOL + i * 64 + lane];
  float As = fmaxf(fmaxf(w[0], w[1]), fmaxf(w[2], w[3]));
#pragma unroll
  for (int off = 1; off < 64; off <<= 1) As = fmaxf(As, __shfl_xor(As, off));
  const float Btot = 1.05e-3f * Sn + 2e-5f * (fabsf(As) + 1.0f) + 1e-3f;

  // ---- phase A: exact-rescore stored winners of candidate columns ----
  const float TA = As - 2.0f * Btot;
  float best = -INFINITY;
  int bk = 0x7FFFFFFF;
#pragma unroll
  for (int i = 0; i < 4; ++i) {
    if (w[i] >= TA) {
      const int col = i * 64 + lane;
      const int tc = (int)(__float_as_uint(w[i]) & 63u);
      const int k = (col >> 4) * SPLITK + tc * 16 + (col & 15);
      const float sc = exact_score(cb4, spq, k);
      if (sc > best || (sc == best && k < bk)) { best = sc; bk = k; }
    }
  }
#pragma unroll
  for (int off = 1; off < 64; off <<= 1) {
    const float ov = __shfl_xor(best, off);
    const int ok = __shfl_xor(bk, off);
    if (ov > best || (ov == best && ok < bk)) { best = ov; bk = ok; }
  }
  const float Estar = best;   // exact score of some real k; all lanes agree

  // ---- phase B: full rescan of columns that could still contain the max ----
#pragma unroll 1
  for (int i = 0; i < 4; ++i) {
    unsigned long long m = __ballot(w[i] + Btot >= Estar);
    while (m) {
      const int e = __builtin_ctzll(m);
      m &= m - 1;
      const int col = i * 64 + e;
      const int k = (col >> 4) * SPLITK + lane * 16 + (col & 15);
      const float sc = exact_score(cb4, spq, k);
      if (sc > best || (sc == best && k < bk)) { best = sc; bk = k; }
    }
  }
  // final cross-lane argmax, min-k on ties (numpy first-max)
#pragma unroll
  for (int off = 1; off < 64; off <<= 1) {
    const float ov = __shfl_xor(best, off);
    const int ok = __shfl_xor(bk, off);
    if (ov > best || (ov == best && ok < bk)) { best = ov; bk = ok; }
  }
  if (lane == 0) out2[row] = (float)bk;
  const int tt = row >> 3, cc = row & 7;
  if (lane < DIM) out0[tt * 256 + lane * 8 + cc] = cb[bk * DIM + lane];
  if (blockIdx.x == 0 && threadIdx.x == 0)
    out1[0] = (float)(klsum[0] * (1.4426 * 0.5) / (double)NROWS);
}

extern "C" void kernel_launch(void* const* d_in, const int* in_sizes, int n_in,
                              void* d_out, int out_size, void* d_ws, size_t ws_size,
                              hipStream_t stream) {
  const float* z  = (const float*)d_in[0];
  const float* cb = (const float*)d_in[2];   // d_in[1]=noise unused (STE cancels)

  char* ws = (char*)d_ws;
  float*      M1 = (float*)(ws + WS_M1);
  double* klsum  = (double*)(ws + WS_KL);
  float*      PQ = (float*)(ws + WS_PQ);
  _Float16*   Ah = (_Float16*)(ws + WS_AH);
  _Float16*   Bh = (_Float16*)(ws + WS_BH);
  float*      W1 = (float*)(ws + WS_W1);

  float* out0 = (float*)d_out;            // 524288
  float* out1 = out0 + 524288;            // 1
  float* out2 = out1 + 1;                 // 16384

  (void)hipMemsetAsync(ws, 0, 4096, stream);       // M1, klsum = 0
  prep_kernel<<<1024, 256, 0, stream>>>(cb, z, Bh, M1, PQ, Ah, klsum);
  dim3 fgrid(64, NSPLIT);
  filter_kernel<<<fgrid, 256, 0, stream>>>(Ah, Bh, W1);
  merge_kernel<<<NROWS / 4, 256, 0, stream>>>(PQ, cb, W1, M1, klsum,
                                              out0, out1, out2);
}